// Round 12
// baseline (195.610 us; speedup 1.0000x reference)
//
#include <hip/hip_runtime.h>
#include <hip/hip_bf16.h>

// HopfieldEnergy: energy_i = -(logsumexp_j(2 * xn_i . an_j) - log M)/2 + 1.0
// M = N = 8192, K = 256. bf16-MFMA matmul + fused row exp-sum.
// *** INSTRUMENTED ROUND (R12): expsum runs RLOOP=3 identical passes (exact
// log(3M) correction in finalize) so its counters top the profile; plus a
// pure register-MFMA probe at identical geometry (issue-cadence reference).
// Single structural variable vs R9: __launch_bounds__(512) with NO min-waves
// (allocator free to use >64 VGPR; R10 showed (512,4) starved to 64). ***

#define MROWS 8192
#define NROWS 8192
#define KDIM  256
#define BM    256
#define BN    64
#define NSPLIT 16
#define RLOOP 3

// 2*log2(e): xb holds (2*log2e)*x_n so exp(2*s) == exp2(acc) directly.
#define XSCALE 2.8853900817779268f

typedef __bf16 bf16x8 __attribute__((ext_vector_type(8)));
typedef float  f32x4  __attribute__((ext_vector_type(4)));

static __device__ __forceinline__ unsigned short f2bf(float f) {
    __hip_bfloat16 h = __float2bfloat16(f);
    union { __hip_bfloat16 h; unsigned short u; } c;
    c.h = h;
    return c.u;
}

// One wave per row. Rows [0,8192) = x, [8192,16384) = a.
// xb = (2*log2e)*x_n, linear. ab = a_n with each row's 16B chunks XOR-swizzled
// by ((j&7)<<4) so expsum can global_load_lds linearly and ds_read swizzled.
__global__ void normalize_kernel(const float* __restrict__ x,
                                 const float* __restrict__ a,
                                 __hip_bfloat16* __restrict__ xb,
                                 __hip_bfloat16* __restrict__ ab) {
    const int lane = threadIdx.x & 63;
    const int gwave = (blockIdx.x * blockDim.x + threadIdx.x) >> 6;
    const bool is_x = gwave < MROWS;
    const int r = is_x ? gwave : gwave - MROWS;
    const float* src = (is_x ? x : a) + (size_t)r * KDIM;

    float4 v = reinterpret_cast<const float4*>(src)[lane];
    float ss = v.x * v.x + v.y * v.y + v.z * v.z + v.w * v.w;
    #pragma unroll
    for (int o = 32; o > 0; o >>= 1) ss += __shfl_xor(ss, o);

    const float inv = 1.0f / fmaxf(sqrtf(ss), 1e-12f);
    const float scale = is_x ? (XSCALE * inv) : inv;

    union { ushort4 u4; unsigned short us[4]; } pk;
    pk.us[0] = f2bf(v.x * scale);
    pk.us[1] = f2bf(v.y * scale);
    pk.us[2] = f2bf(v.z * scale);
    pk.us[3] = f2bf(v.w * scale);

    if (is_x) {
        reinterpret_cast<ushort4*>(xb + (size_t)r * KDIM)[lane] = pk.u4;
    } else {
        char* base = (char*)(ab + (size_t)r * KDIM);
        const int off = (lane * 8) ^ ((r & 7) << 4);  // pre-swizzle source side
        *reinterpret_cast<ushort4*>(base + off) = pk.u4;
    }
}

// Pure register-MFMA cadence probe: same geometry as expsum (512 thr, 1024
// waves-worth grid), f=2 dep structure (4 rotating acc), no LDS/barriers,
// ~95 live VGPR, no launch_bounds. 1280 MFMA/wave -> ~82us if cadence-clean.
__global__ void mfma_probe_kernel(const __hip_bfloat16* __restrict__ xb,
                                  float* __restrict__ scratch) {
    const int lane = threadIdx.x & 63;
    const int w = threadIdx.x >> 6;

    bf16x8 afrag[2][8];
    const int arow = ((blockIdx.x & 31) * 8 + w) * 32 + (lane & 15);
    const int kb = (lane >> 4) * 8;
    #pragma unroll
    for (int f = 0; f < 2; ++f)
        #pragma unroll
        for (int ks = 0; ks < 8; ++ks)
            afrag[f][ks] = *reinterpret_cast<const bf16x8*>(
                xb + (size_t)(arow + f * 16) * KDIM + ks * 32 + kb);

    f32x4 acc[2][2];
    #pragma unroll
    for (int f = 0; f < 2; ++f) {
        acc[f][0] = (f32x4){0.f, 0.f, 0.f, 0.f};
        acc[f][1] = (f32x4){0.f, 0.f, 0.f, 0.f};
    }

    for (int it = 0; it < 40; ++it) {
        #pragma unroll
        for (int ks = 0; ks < 8; ++ks) {
            bf16x8 b0 = afrag[ks & 1][ks];
            bf16x8 b1 = afrag[(ks + 1) & 1][(ks + 3) & 7];
            acc[0][0] = __builtin_amdgcn_mfma_f32_16x16x32_bf16(
                afrag[0][ks], b0, acc[0][0], 0, 0, 0);
            acc[1][0] = __builtin_amdgcn_mfma_f32_16x16x32_bf16(
                afrag[1][ks], b0, acc[1][0], 0, 0, 0);
            acc[0][1] = __builtin_amdgcn_mfma_f32_16x16x32_bf16(
                afrag[0][ks], b1, acc[0][1], 0, 0, 0);
            acc[1][1] = __builtin_amdgcn_mfma_f32_16x16x32_bf16(
                afrag[1][ks], b1, acc[1][1], 0, 0, 0);
        }
    }

    float s = 0.f;
    #pragma unroll
    for (int f = 0; f < 2; ++f)
        #pragma unroll
        for (int g = 0; g < 2; ++g)
            #pragma unroll
            for (int r = 0; r < 4; ++r) s += acc[f][g][r];
    scratch[blockIdx.x * 512 + threadIdx.x] = s;  // keep live (rule #17)
}

// grid (32, 16), 512 threads (8 waves x 32 rows, f=2, ~115 live VGPR).
// __launch_bounds__(512) ONLY -- no min-waves: allocator unconstrained.
// RLOOP=3 identical passes (rowsum = 3 * true sum; finalize corrects).
__global__ __launch_bounds__(512) void expsum_kernel(
    const __hip_bfloat16* __restrict__ xb,
    const __hip_bfloat16* __restrict__ ab,
    float* __restrict__ partial) {
    __shared__ __attribute__((aligned(16))) char lds[2][BN * 512];

    const int tid = threadIdx.x;
    const int lane = tid & 63;
    const int w = tid >> 6;          // 0..7
    const int mbase = blockIdx.x * BM;
    const int jstart = blockIdx.y * (NROWS / NSPLIT);
    const int nsteps = (NROWS / NSPLIT) / BN;  // 8

    bf16x8 afrag[2][8];
    const int arow = mbase + w * 32 + (lane & 15);
    const int kb = (lane >> 4) * 8;
    #pragma unroll
    for (int f = 0; f < 2; ++f)
        #pragma unroll
        for (int ks = 0; ks < 8; ++ks)
            afrag[f][ks] = *reinterpret_cast<const bf16x8*>(
                xb + (size_t)(arow + f * 16) * KDIM + ks * 32 + kb);

    auto stage = [&](int buf, int j0) {
        const char* src = (const char*)ab + (size_t)j0 * 512;
        #pragma unroll
        for (int i = 0; i < 4; ++i) {
            const int chunk = w * 4 + i;  // 32 chunks x 1 KB = 32 KB tile
            __builtin_amdgcn_global_load_lds(
                (const __attribute__((address_space(1))) void*)
                    (src + chunk * 1024 + lane * 16),
                (__attribute__((address_space(3))) void*)
                    (&lds[buf][chunk * 1024]),
                16, 0, 0);
        }
    };

    float rowsum[2][4] = {{0.f, 0.f, 0.f, 0.f}, {0.f, 0.f, 0.f, 0.f}};
    const int cb = (lane >> 4) * 16;  // byte col base within a k-group
    const int rl = lane & 15;

    for (int rep = 0; rep < RLOOP; ++rep) {
        stage(0, jstart);
        for (int step = 0; step < nsteps; ++step) {
            __syncthreads();  // drains vmcnt: stage(step) landed; prev reads done
            if (step + 1 < nsteps) stage((step + 1) & 1, jstart + (step + 1) * BN);
            const char* L = lds[step & 1];

            #pragma unroll
            for (int sub = 0; sub < 2; ++sub) {
                const int r0 = rl + sub * 32;
                const int r1 = r0 + 16;

                f32x4 acc[2][2];
                #pragma unroll
                for (int f = 0; f < 2; ++f) {
                    acc[f][0] = (f32x4){0.f, 0.f, 0.f, 0.f};
                    acc[f][1] = (f32x4){0.f, 0.f, 0.f, 0.f};
                }

                #pragma unroll
                for (int ks = 0; ks < 8; ++ks) {
                    const int bcol = ks * 64 + cb;
                    bf16x8 b0 = *reinterpret_cast<const bf16x8*>(
                        &L[r0 * 512 + (bcol ^ ((r0 & 7) << 4))]);
                    bf16x8 b1 = *reinterpret_cast<const bf16x8*>(
                        &L[r1 * 512 + (bcol ^ ((r1 & 7) << 4))]);
                    #pragma unroll
                    for (int f = 0; f < 2; ++f) {
                        acc[f][0] = __builtin_amdgcn_mfma_f32_16x16x32_bf16(
                            afrag[f][ks], b0, acc[f][0], 0, 0, 0);
                        acc[f][1] = __builtin_amdgcn_mfma_f32_16x16x32_bf16(
                            afrag[f][ks], b1, acc[f][1], 0, 0, 0);
                    }
                }

                #pragma unroll
                for (int f = 0; f < 2; ++f)
                    #pragma unroll
                    for (int g = 0; g < 2; ++g)
                        #pragma unroll
                        for (int r = 0; r < 4; ++r)
                            rowsum[f][r] += __builtin_amdgcn_exp2f(acc[f][g][r]);
            }
        }
        __syncthreads();  // rep boundary: all reads of lds done before restage
    }

    // sum across the 16 lanes sharing (lane>>4)
    #pragma unroll
    for (int f = 0; f < 2; ++f)
        #pragma unroll
        for (int r = 0; r < 4; ++r) {
            float s = rowsum[f][r];
            s += __shfl_xor(s, 1);
            s += __shfl_xor(s, 2);
            s += __shfl_xor(s, 4);
            s += __shfl_xor(s, 8);
            rowsum[f][r] = s;
        }

    if ((lane & 15) == 0) {
        const int rbase = mbase + w * 32 + (lane >> 4) * 4;
        #pragma unroll
        for (int f = 0; f < 2; ++f)
            #pragma unroll
            for (int r = 0; r < 4; ++r)
                partial[(size_t)blockIdx.y * MROWS + rbase + f * 16 + r] = rowsum[f][r];
    }
}

__global__ void finalize_kernel(const float* __restrict__ partial,
                                float* __restrict__ out) {
    const int i = blockIdx.x * blockDim.x + threadIdx.x;
    float s = 0.f;
    #pragma unroll
    for (int p = 0; p < NSPLIT; ++p) s += partial[(size_t)p * MROWS + i];
    // s = RLOOP * Sum_j e^{2 s_ij}; log(s/RLOOP) = log s - log RLOOP (exact corr.)
    out[i] = -0.5f * (logf(s) - logf((float)RLOOP * (float)NROWS)) + 1.0f;
}

extern "C" void kernel_launch(void* const* d_in, const int* in_sizes, int n_in,
                              void* d_out, int out_size, void* d_ws, size_t ws_size,
                              hipStream_t stream) {
    const float* x = (const float*)d_in[0];
    const float* a = (const float*)d_in[1];
    float* out = (float*)d_out;

    char* ws = (char*)d_ws;
    size_t off = 0;
    __hip_bfloat16* xb = (__hip_bfloat16*)(ws + off); off += (size_t)MROWS * KDIM * 2;  // 4 MiB
    __hip_bfloat16* ab = (__hip_bfloat16*)(ws + off); off += (size_t)NROWS * KDIM * 2;  // 4 MiB
    float* partial     = (float*)(ws + off);          off += (size_t)NSPLIT * MROWS * 4;
    float* scratch     = (float*)(ws + off);          // probe output, 2 MiB

    normalize_kernel<<<(2 * MROWS) / 4, 256, 0, stream>>>(x, a, xb, ab);
    mfma_probe_kernel<<<1024, 512, 0, stream>>>(xb, scratch);
    expsum_kernel<<<dim3(MROWS / BM, NSPLIT), 512, 0, stream>>>(xb, ab, partial);
    finalize_kernel<<<MROWS / 256, 256, 0, stream>>>(partial, out);
}

// Round 13
// 53.874 us; speedup vs baseline: 3.6309x; 3.6309x over previous
//
#include <hip/hip_runtime.h>
#include <hip/hip_bf16.h>

// HopfieldEnergy: energy_i = -(logsumexp_j(2 * xn_i . an_j) - log M)/2 + 1.0
// M = N = 8192, K = 256. bf16-MFMA matmul + fused row exp-sum.
// R12 probe: MfmaUtil tracks occupancy (1.5 w/SIMD -> 50%, 3.5 -> 76%).
// R13: mfma_f32_32x32x16_bf16 at f=1 (32 rows/wave): afrag 64 VGPR, ~115
// total -> 4 blocks/CU (4 waves/SIMD), half the MFMA issue slots of 16x16.

#define MROWS 8192
#define NROWS 8192
#define KDIM  256
#define BM    128
#define BN    32
#define NSPLIT 16

// 2*log2(e): xb holds (2*log2e)*x_n so exp(2*s) == exp2(acc) directly.
#define XSCALE 2.8853900817779268f

typedef __bf16 bf16x8 __attribute__((ext_vector_type(8)));
typedef float  f32x16 __attribute__((ext_vector_type(16)));

static __device__ __forceinline__ unsigned short f2bf(float f) {
    __hip_bfloat16 h = __float2bfloat16(f);
    union { __hip_bfloat16 h; unsigned short u; } c;
    c.h = h;
    return c.u;
}

// One wave per row. Rows [0,8192) = x, [8192,16384) = a.
// xb = (2*log2e)*x_n, linear. ab = a_n with each row's 16B chunks XOR-swizzled
// by ((j&7)<<4) so expsum can global_load_lds linearly and ds_read swizzled.
__global__ void normalize_kernel(const float* __restrict__ x,
                                 const float* __restrict__ a,
                                 __hip_bfloat16* __restrict__ xb,
                                 __hip_bfloat16* __restrict__ ab) {
    const int lane = threadIdx.x & 63;
    const int gwave = (blockIdx.x * blockDim.x + threadIdx.x) >> 6;
    const bool is_x = gwave < MROWS;
    const int r = is_x ? gwave : gwave - MROWS;
    const float* src = (is_x ? x : a) + (size_t)r * KDIM;

    float4 v = reinterpret_cast<const float4*>(src)[lane];
    float ss = v.x * v.x + v.y * v.y + v.z * v.z + v.w * v.w;
    #pragma unroll
    for (int o = 32; o > 0; o >>= 1) ss += __shfl_xor(ss, o);

    const float inv = 1.0f / fmaxf(sqrtf(ss), 1e-12f);
    const float scale = is_x ? (XSCALE * inv) : inv;

    union { ushort4 u4; unsigned short us[4]; } pk;
    pk.us[0] = f2bf(v.x * scale);
    pk.us[1] = f2bf(v.y * scale);
    pk.us[2] = f2bf(v.z * scale);
    pk.us[3] = f2bf(v.w * scale);

    if (is_x) {
        reinterpret_cast<ushort4*>(xb + (size_t)r * KDIM)[lane] = pk.u4;
    } else {
        char* base = (char*)(ab + (size_t)r * KDIM);
        const int off = (lane * 8) ^ ((r & 7) << 4);  // pre-swizzle source side
        *reinterpret_cast<ushort4*>(base + off) = pk.u4;
    }
}

// grid (MROWS/BM=64, NSPLIT=16) = 1024 blocks, 256 thr (4 waves x 32 rows).
// 32x32x16 MFMA: lane supplies A row (lane&31) and B col (lane&31), k chunk
// (lane>>5)*8 (identical k-addressing for A and B -> permutation-safe).
// afrag 64 VGPR + acc 16 + rowsum 16 + temps ~= 115 -> 4 blocks/CU
// (16 waves/CU, 4/SIMD). launch_bounds(256,3) caps at ~170 (no hard-cap
// spill risk, R10 lesson). LDS 2 x 16KB double buffer, 1 barrier/step.
// C/D layout (m74/m101): col=lane&31, row=(reg&3)+8*(reg>>2)+4*(lane>>5).
__global__ __launch_bounds__(256, 3) void expsum_kernel(
    const __hip_bfloat16* __restrict__ xb,
    const __hip_bfloat16* __restrict__ ab,
    float* __restrict__ partial) {
    __shared__ __attribute__((aligned(16))) char lds[2][BN * 512];

    const int tid = threadIdx.x;
    const int lane = tid & 63;
    const int w = tid >> 6;          // 0..3
    const int hi = lane >> 5;        // 0/1: k-half selector
    const int cl = lane & 31;        // A row / B col within the 32-group
    const int mbase = blockIdx.x * BM;
    const int jstart = blockIdx.y * (NROWS / NSPLIT);
    const int nsteps = (NROWS / NSPLIT) / BN;  // 16

    // A fragments: row = cl, k = ks*16 + hi*8 + [0..8): 16 x 4 VGPR = 64.
    bf16x8 afrag[16];
    const int arow = mbase + w * 32 + cl;
    #pragma unroll
    for (int ks = 0; ks < 16; ++ks)
        afrag[ks] = *reinterpret_cast<const bf16x8*>(
            xb + (size_t)arow * KDIM + ks * 16 + hi * 8);

    auto stage = [&](int buf, int j0) {
        const char* src = (const char*)ab + (size_t)j0 * 512;
        #pragma unroll
        for (int i = 0; i < 4; ++i) {
            const int off = (tid + 256 * i) * 16;  // 16KB tile, linear
            __builtin_amdgcn_global_load_lds(
                (const __attribute__((address_space(1))) void*)(src + off),
                (__attribute__((address_space(3))) void*)(&lds[buf][off]),
                16, 0, 0);
        }
    };

    float rowsum[16];
    #pragma unroll
    for (int e = 0; e < 16; ++e) rowsum[e] = 0.f;

    const int sw = (cl & 7) << 4;
    const int rbase = cl * 512;      // B row (a_n index j0+cl) byte base

    stage(0, jstart);

    for (int step = 0; step < nsteps; ++step) {
        __syncthreads();  // drains vmcnt: stage(step) landed; prev reads done
        if (step + 1 < nsteps) stage((step + 1) & 1, jstart + (step + 1) * BN);
        const char* L = lds[step & 1];

        f32x16 acc = {0.f, 0.f, 0.f, 0.f, 0.f, 0.f, 0.f, 0.f,
                      0.f, 0.f, 0.f, 0.f, 0.f, 0.f, 0.f, 0.f};
        #pragma unroll
        for (int ks = 0; ks < 16; ++ks) {
            bf16x8 b = *reinterpret_cast<const bf16x8*>(
                &L[rbase + ((ks * 32 + hi * 16) ^ sw)]);
            acc = __builtin_amdgcn_mfma_f32_32x32x16_bf16(
                afrag[ks], b, acc, 0, 0, 0);
        }

        // acc[e] = (2log2e)*s[x-row=(e&3)+8*(e>>2)+4*hi][col=j0+cl]
        #pragma unroll
        for (int e = 0; e < 16; ++e)
            rowsum[e] += __builtin_amdgcn_exp2f(acc[e]);
    }

    // sum over the 32 cols: butterfly over lane bits 0..4 (stays in hi half)
    #pragma unroll
    for (int e = 0; e < 16; ++e) {
        float s = rowsum[e];
        s += __shfl_xor(s, 1);
        s += __shfl_xor(s, 2);
        s += __shfl_xor(s, 4);
        s += __shfl_xor(s, 8);
        s += __shfl_xor(s, 16);
        rowsum[e] = s;
    }

    if (cl == 0) {  // lanes 0 and 32: each writes its hi-half's 16 rows
        #pragma unroll
        for (int e = 0; e < 16; ++e) {
            const int row = (e & 3) + 8 * (e >> 2) + 4 * hi;
            partial[(size_t)blockIdx.y * MROWS + mbase + w * 32 + row] =
                rowsum[e];
        }
    }
}

__global__ void finalize_kernel(const float* __restrict__ partial,
                                float* __restrict__ out) {
    const int i = blockIdx.x * blockDim.x + threadIdx.x;
    float s = 0.f;
    #pragma unroll
    for (int p = 0; p < NSPLIT; ++p) s += partial[(size_t)p * MROWS + i];
    // energy = -(log(sum)-log M)/2 + 0.5||xn||^2 + 0.5 max||an||^2, norms == 1
    out[i] = -0.5f * (logf(s) - logf((float)NROWS)) + 1.0f;
}

extern "C" void kernel_launch(void* const* d_in, const int* in_sizes, int n_in,
                              void* d_out, int out_size, void* d_ws, size_t ws_size,
                              hipStream_t stream) {
    const float* x = (const float*)d_in[0];
    const float* a = (const float*)d_in[1];
    float* out = (float*)d_out;

    char* ws = (char*)d_ws;
    size_t off = 0;
    __hip_bfloat16* xb = (__hip_bfloat16*)(ws + off); off += (size_t)MROWS * KDIM * 2;  // 4 MiB
    __hip_bfloat16* ab = (__hip_bfloat16*)(ws + off); off += (size_t)NROWS * KDIM * 2;  // 4 MiB
    float* partial     = (float*)(ws + off);          // NSPLIT*MROWS*4 = 512 KiB

    normalize_kernel<<<(2 * MROWS) / 4, 256, 0, stream>>>(x, a, xb, ab);
    expsum_kernel<<<dim3(MROWS / BM, NSPLIT), 256, 0, stream>>>(xb, ab, partial);
    finalize_kernel<<<MROWS / 256, 256, 0, stream>>>(partial, out);
}